// Round 7
// baseline (193.539 us; speedup 1.0000x reference)
//
#include <hip/hip_runtime.h>

#define N_NODES 25000
#define N_EDGES 250000
#define F_IN 32
#define F_OUT 32
#define ED 6
#define H1 64
#define H2 128
#define NBLK 977                 // ceil(250000/256)
#define K_TOT 4160               // ushorts per o-row: 4096 (h2*xs) + 32 (b3) + 32 pad
#define W3S_USHORTS (32*K_TOT)   // 133120 = 266KB, L2-resident
#define W2S_USHORTS (H2*H1)      // 8192 = 16KB
#define SCAN_BLOCKS 98           // ceil(25000/256)

typedef float f32x4 __attribute__((ext_vector_type(4)));
typedef short s16x8 __attribute__((ext_vector_type(8)));
typedef unsigned int u32x4 __attribute__((ext_vector_type(4)));
typedef unsigned int u32x2 __attribute__((ext_vector_type(2)));

union ABu { u32x4 u; s16x8 s; };

// HW packed f32->bf16 (RNE): S0 -> low ushort, S1 -> high ushort.
__device__ __forceinline__ unsigned cvt_pk_bf16(float lo, float hi) {
    unsigned r;
    asm("v_cvt_pk_bf16_f32 %0, %1, %2" : "=v"(r) : "v"(lo), "v"(hi));
    return r;
}
__device__ __forceinline__ unsigned short f2bf(float f) {   // init kernels only
    union { float f; unsigned u; } v; v.f = f;
    return (unsigned short)((v.u + 0x7FFF + ((v.u >> 16) & 1)) >> 16);
}
__device__ __forceinline__ float bf2f(unsigned short h) {
    union { unsigned u; float f; } v; v.u = ((unsigned)h) << 16;
    return v.f;
}

// ---------------- sort machinery -------------------------------------------
__global__ __launch_bounds__(256) void ecc_zero_cnt(unsigned* __restrict__ cnt) {
    int i = blockIdx.x * 256 + threadIdx.x;
    if (i < N_NODES) cnt[i] = 0u;
}

__global__ __launch_bounds__(256) void ecc_hist(
    const int* __restrict__ dst, unsigned* __restrict__ cnt,
    unsigned* __restrict__ rank)
{
    int e = blockIdx.x * 256 + threadIdx.x;
    if (e < N_EDGES) rank[e] = atomicAdd(&cnt[dst[e]], 1u);
}

__global__ __launch_bounds__(256) void ecc_scan1(
    const unsigned* __restrict__ cnt, unsigned* __restrict__ off,
    unsigned* __restrict__ bsum)
{
    __shared__ unsigned s[256];
    const int t = threadIdx.x, i = blockIdx.x * 256 + t;
    unsigned v = (i < N_NODES) ? cnt[i] : 0u;
    s[t] = v; __syncthreads();
    #pragma unroll
    for (int d = 1; d < 256; d <<= 1) {
        unsigned add = (t >= d) ? s[t - d] : 0u;
        __syncthreads(); s[t] += add; __syncthreads();
    }
    if (i < N_NODES) off[i] = s[t] - v;       // exclusive
    if (t == 255) bsum[blockIdx.x] = s[255];
}

__global__ __launch_bounds__(128) void ecc_scan2(
    const unsigned* __restrict__ bsum, unsigned* __restrict__ bsumx)
{
    __shared__ unsigned s[128];
    const int t = threadIdx.x;
    unsigned v = (t < SCAN_BLOCKS) ? bsum[t] : 0u;
    s[t] = v; __syncthreads();
    #pragma unroll
    for (int d = 1; d < 128; d <<= 1) {
        unsigned add = (t >= d) ? s[t - d] : 0u;
        __syncthreads(); s[t] += add; __syncthreads();
    }
    if (t < SCAN_BLOCKS) bsumx[t] = s[t] - v; // exclusive
}

__global__ __launch_bounds__(256) void ecc_scan3(
    unsigned* __restrict__ off, const unsigned* __restrict__ bsumx)
{
    int i = blockIdx.x * 256 + threadIdx.x;
    if (i < N_NODES) off[i] += bsumx[blockIdx.x];
    if (i == 0) off[N_NODES] = N_EDGES;
}

__global__ __launch_bounds__(256) void ecc_perm(
    const int* __restrict__ dst, const unsigned* __restrict__ off,
    const unsigned* __restrict__ rank, unsigned* __restrict__ perm)
{
    int e = blockIdx.x * 256 + threadIdx.x;
    if (e < N_EDGES) perm[off[dst[e]] + rank[e]] = (unsigned)e;
}

// ---------------- weight repacks -------------------------------------------
__global__ __launch_bounds__(256) void ecc_w3s(
    const float* __restrict__ W3, const float* __restrict__ b3,
    unsigned short* __restrict__ w3s)
{
    int idx = blockIdx.x * 256 + threadIdx.x;
    if (idx >= W3S_USHORTS) return;
    int o = idx / K_TOT, kp = idx % K_TOT;
    float v = 0.f;
    if (kp < 4096)      { int k = kp >> 5, i = kp & 31; v = W3[(o * 32 + i) * 128 + k]; }
    else if (kp < 4128) { v = b3[o * 32 + (kp - 4096)]; }
    w3s[idx] = f2bf(v);
}

__global__ __launch_bounds__(256) void ecc_w2s(
    const float* __restrict__ W2, unsigned short* __restrict__ w2s)
{
    int idx = blockIdx.x * 256 + threadIdx.x;
    if (idx < W2S_USHORTS) w2s[idx] = f2bf(W2[idx]);
}

// ---------------- main: MLP + dynamic-filter GEMM, atomic-free -------------
__global__ __launch_bounds__(256, 2) void ecc_main(
    const float* __restrict__ x,   const float* __restrict__ ea,
    const float* __restrict__ W1,  const float* __restrict__ b1,
    const unsigned short* __restrict__ w2s, const float* __restrict__ b2,
    const unsigned short* __restrict__ w3s,
    const int* __restrict__ src,   const unsigned* __restrict__ perm,
    unsigned short* __restrict__ msg)
{
    // 64KB. First 32KB doubles as h1s [slot][64] bf16 during phase 0; then
    // h2s [slot][128] bf16. XOR-swizzled with ((row&7)<<4). Wave-private rows.
    __shared__ unsigned short sm[256 * H2];

    const int t = threadIdx.x;
    const int tile = blockIdx.x * 256;
    const int slot = tile + t;
    const bool ev = (slot < N_EDGES);
    const unsigned je = ev ? perm[slot] : 0u;

    const int w  = t >> 6;
    const int l  = t & 63;
    const int lr = l & 15;
    const int kg = l >> 4;

    // ---------------- phase 0a: L1 on VALU -> h1s ---------------------------
    {
        float a[ED];
        #pragma unroll
        for (int c = 0; c < ED; ++c) a[c] = ev ? ea[(long)je * ED + c] : 0.f;

        float h1[H1];
        #pragma unroll
        for (int o = 0; o < H1; ++o) {
            float acc = b1[o];
            #pragma unroll
            for (int c = 0; c < ED; ++c) acc = fmaf(W1[o * ED + c], a[c], acc);
            h1[o] = fmaxf(acc, 0.f);
        }
        #pragma unroll
        for (int q = 0; q < 8; ++q) {
            u32x4 pk;
            #pragma unroll
            for (int j = 0; j < 4; ++j)
                pk[j] = cvt_pk_bf16(h1[q*8 + 2*j], h1[q*8 + 2*j + 1]);
            const int boff = (t * 128 + q * 16) ^ ((t & 7) << 4);
            *(u32x4*)((char*)sm + boff) = pk;
        }
    }

    // ---------------- per-lane xs gather (slot-indexed via perm) ------------
    float xsf[4][8];
    #pragma unroll
    for (int mt = 0; mt < 4; ++mt) {
        const int er = tile + w * 64 + mt * 16 + lr;
        if (er < N_EDGES) {
            const float4* xp = (const float4*)(x + (long)src[perm[er]] * F_IN + kg * 8);
            float4 v0 = xp[0], v1 = xp[1];
            xsf[mt][0] = v0.x; xsf[mt][1] = v0.y; xsf[mt][2] = v0.z; xsf[mt][3] = v0.w;
            xsf[mt][4] = v1.x; xsf[mt][5] = v1.y; xsf[mt][6] = v1.z; xsf[mt][7] = v1.w;
        } else {
            #pragma unroll
            for (int j = 0; j < 8; ++j) xsf[mt][j] = 0.f;
        }
    }

    __syncthreads();

    // ---------------- phase 0b: layer 2 via MFMA ----------------------------
    {
        s16x8 hb[4][2];
        #pragma unroll
        for (int ne = 0; ne < 4; ++ne) {
            const int er = w * 64 + ne * 16 + lr;
            #pragma unroll
            for (int ks = 0; ks < 2; ++ks) {
                const int boff = (er * 128 + ks * 64 + kg * 16) ^ ((er & 7) << 4);
                hb[ne][ks] = *(const s16x8*)((const char*)sm + boff);
            }
        }
        __syncthreads();   // h1 reads done before h2 overwrites region

        #pragma unroll
        for (int mo = 0; mo < 8; ++mo) {
            s16x8 a2[2];
            #pragma unroll
            for (int ks = 0; ks < 2; ++ks)
                a2[ks] = *(const s16x8*)(w2s + (mo*16 + lr) * 64 + ks*32 + kg*8);
            const float4 bv = *(const float4*)(b2 + mo*16 + kg*4);
            #pragma unroll
            for (int ne = 0; ne < 4; ++ne) {
                f32x4 c = (f32x4){0.f, 0.f, 0.f, 0.f};
                c = __builtin_amdgcn_mfma_f32_16x16x32_bf16(a2[0], hb[ne][0], c, 0,0,0);
                c = __builtin_amdgcn_mfma_f32_16x16x32_bf16(a2[1], hb[ne][1], c, 0,0,0);
                const unsigned p0 = cvt_pk_bf16(fmaxf(c[0]+bv.x, 0.f), fmaxf(c[1]+bv.y, 0.f));
                const unsigned p1 = cvt_pk_bf16(fmaxf(c[2]+bv.z, 0.f), fmaxf(c[3]+bv.w, 0.f));
                const int er = w * 64 + ne * 16 + lr;
                const int boff = (er * 256 + (mo*16 + kg*4) * 2) ^ ((er & 7) << 4);
                *(u32x2*)((char*)sm + boff) = (u32x2){p0, p1};
            }
        }
    }

    f32x4 acc[4][2];
    #pragma unroll
    for (int mt = 0; mt < 4; ++mt)
        #pragma unroll
        for (int nt = 0; nt < 2; ++nt) acc[mt][nt] = (f32x4){0.f,0.f,0.f,0.f};

    const unsigned short* bb0 = w3s + (long)lr * K_TOT + kg * 8;
    const unsigned short* bb1 = bb0 + 16L * K_TOT;

    __syncthreads();   // h2s ready; no more barriers

    // ---------------- K loop: 16 chunks x 8 ksteps + b3 step ----------------
    #pragma unroll 1
    for (int c = 0; c < 16; ++c) {
        // prefetch the whole chunk's B-frags (static-indexed regs)
        s16x8 bf0[8], bf1[8];
        #pragma unroll
        for (int kk = 0; kk < 8; ++kk) {
            bf0[kk] = *(const s16x8*)(bb0 + (c*8 + kk) * 32);
            bf1[kk] = *(const s16x8*)(bb1 + (c*8 + kk) * 32);
        }
        s16x8 h2v[4];
        #pragma unroll
        for (int mt = 0; mt < 4; ++mt) {
            const int row = w * 64 + mt * 16 + lr;
            const int boff = (row * 256 + c * 16) ^ ((row & 7) << 4);
            h2v[mt] = *(const s16x8*)((const char*)sm + boff);
        }
        #pragma unroll
        for (int kk = 0; kk < 8; ++kk) {
            #pragma unroll
            for (int mt = 0; mt < 4; ++mt) {
                const float hf = bf2f((unsigned short)h2v[mt][kk]);
                ABu af;
                #pragma unroll
                for (int j = 0; j < 4; ++j)
                    af.u[j] = cvt_pk_bf16(hf * xsf[mt][2*j], hf * xsf[mt][2*j+1]);
                acc[mt][0] = __builtin_amdgcn_mfma_f32_16x16x32_bf16(af.s, bf0[kk], acc[mt][0], 0,0,0);
                acc[mt][1] = __builtin_amdgcn_mfma_f32_16x16x32_bf16(af.s, bf1[kk], acc[mt][1], 0,0,0);
            }
        }
    }
    {   // b3 k-step (ks = 128): A = bf16(xs)
        s16x8 bfrag0 = *(const s16x8*)(bb0 + 128 * 32);
        s16x8 bfrag1 = *(const s16x8*)(bb1 + 128 * 32);
        #pragma unroll
        for (int mt = 0; mt < 4; ++mt) {
            ABu af;
            #pragma unroll
            for (int j = 0; j < 4; ++j)
                af.u[j] = cvt_pk_bf16(xsf[mt][2*j], xsf[mt][2*j+1]);
            acc[mt][0] = __builtin_amdgcn_mfma_f32_16x16x32_bf16(af.s, bfrag0, acc[mt][0], 0,0,0);
            acc[mt][1] = __builtin_amdgcn_mfma_f32_16x16x32_bf16(af.s, bfrag1, acc[mt][1], 0,0,0);
        }
    }

    // ---------------- epilogue: coalesced bf16 msg store (slot-indexed) -----
    // C layout: col = lane&15 (o), row = (lane>>4)*4 + reg (slot)
    #pragma unroll
    for (int mt = 0; mt < 4; ++mt) {
        #pragma unroll
        for (int r = 0; r < 4; ++r) {
            const int j = tile + w * 64 + mt * 16 + kg * 4 + r;
            if (j < N_EDGES) {
                const unsigned u = cvt_pk_bf16(acc[mt][0][r], acc[mt][1][r]);
                msg[(long)j * 32 + lr]      = (unsigned short)(u & 0xFFFFu);
                msg[(long)j * 32 + 16 + lr] = (unsigned short)(u >> 16);
            }
        }
    }
}

// ---------------- gather-mean + relu (replaces finalize) -------------------
__global__ __launch_bounds__(256) void ecc_gather(
    const unsigned short* __restrict__ msg, const unsigned* __restrict__ off,
    float* __restrict__ out)
{
    const int t = threadIdx.x;
    const int o = t & 31;
    const int n = blockIdx.x * 8 + (t >> 5);
    if (n >= N_NODES) return;
    const unsigned lo = off[n], hi = off[n + 1];
    float s = 0.f;
    for (unsigned j = lo; j < hi; ++j) s += bf2f(msg[(long)j * 32 + o]);
    const float dg = fmaxf((float)(hi - lo), 1.f);
    out[(long)n * 32 + o] = fmaxf(s / dg, 0.f);
}

extern "C" void kernel_launch(void* const* d_in, const int* in_sizes, int n_in,
                              void* d_out, int out_size, void* d_ws, size_t ws_size,
                              hipStream_t stream) {
    const float* x   = (const float*)d_in[0];
    const float* ea  = (const float*)d_in[1];
    const float* W1  = (const float*)d_in[2];
    const float* b1  = (const float*)d_in[3];
    const float* W2  = (const float*)d_in[4];
    const float* b2  = (const float*)d_in[5];
    const float* W3  = (const float*)d_in[6];
    const float* b3  = (const float*)d_in[7];
    const int*   src = (const int*)d_in[8];
    const int*   dst = (const int*)d_in[9];
    float* out = (float*)d_out;

    char* p = (char*)d_ws;
    unsigned short* w3s = (unsigned short*)p; p += 266240;          // 133120 ush
    unsigned short* w2s = (unsigned short*)p; p += 16384;
    unsigned* cnt   = (unsigned*)p; p += 100096;                    // 25000 u32
    unsigned* off   = (unsigned*)p; p += 100352;                    // 25001 u32
    unsigned* bsum  = (unsigned*)p; p += 512;
    unsigned* bsumx = (unsigned*)p; p += 512;
    unsigned* rank  = (unsigned*)p; p += 1000192;                   // 250000 u32
    unsigned* perm  = (unsigned*)p; p += 1000192;
    unsigned short* msg = (unsigned short*)p;                       // 250000*32 bf16 = 16MB

    ecc_zero_cnt<<<(N_NODES + 255) / 256, 256, 0, stream>>>(cnt);
    ecc_w3s<<<(W3S_USHORTS + 255) / 256, 256, 0, stream>>>(W3, b3, w3s);
    ecc_w2s<<<(W2S_USHORTS + 255) / 256, 256, 0, stream>>>(W2, w2s);
    ecc_hist<<<NBLK, 256, 0, stream>>>(dst, cnt, rank);
    ecc_scan1<<<SCAN_BLOCKS, 256, 0, stream>>>(cnt, off, bsum);
    ecc_scan2<<<1, 128, 0, stream>>>(bsum, bsumx);
    ecc_scan3<<<SCAN_BLOCKS, 256, 0, stream>>>(off, bsumx);
    ecc_perm<<<NBLK, 256, 0, stream>>>(dst, off, rank, perm);
    ecc_main<<<NBLK, 256, 0, stream>>>(x, ea, W1, b1, w2s, b2, w3s, src, perm, msg);
    ecc_gather<<<(N_NODES + 7) / 8, 256, 0, stream>>>(msg, off, out);
}